// Round 3
// baseline (488.612 us; speedup 1.0000x reference)
//
#include <hip/hip_runtime.h>

// Segment-sum via counting sort + gather reduce (no float atomics).
// H: [N=1.6M, 128] f32, X_node: [N] i32, out: [V=50000, 128] f32.
//
// Phases:
//  1. hist[v]   = count of rows with X_node==v           (int atomics)
//  2. offsets   = exclusive scan(hist)                   (one 1024-thread block)
//  3. order[]   = row indices grouped by bucket          (int atomics)
//  4. one wave per bucket: lanes 0-31 gather row r, lanes 32-63 row r+1
//     (float4/lane -> 1 KB per load instr, 8 rows in flight), shfl-combine,
//     single non-atomic store.

#define D 128
#define BLOCK 256
#define SCAN_T 1024

// ---------------- phase 1: histogram ----------------
__global__ void hist_kernel(const int* __restrict__ idx, int* __restrict__ hist, int n) {
    int i = blockIdx.x * blockDim.x + threadIdx.x;
    int stride = gridDim.x * blockDim.x;
    for (; i < n; i += stride) atomicAdd(&hist[idx[i]], 1);
}

// ---------------- phase 2: single-block exclusive scan ----------------
__global__ void __launch_bounds__(SCAN_T) scan_kernel(const int* __restrict__ hist,
                                                      int* __restrict__ offsets,
                                                      int* __restrict__ cursor, int V) {
    __shared__ int lds[SCAN_T];
    const int t = threadIdx.x;
    const int K = (V + SCAN_T - 1) / SCAN_T;
    const int base = t * K;
    int s = 0;
    for (int i = 0; i < K; ++i) { int g = base + i; if (g < V) s += hist[g]; }
    lds[t] = s; __syncthreads();
    for (int off = 1; off < SCAN_T; off <<= 1) {   // Hillis-Steele inclusive
        int add = (t >= off) ? lds[t - off] : 0;
        __syncthreads();
        lds[t] += add;
        __syncthreads();
    }
    int run = lds[t] - s;                           // exclusive prefix
    for (int i = 0; i < K; ++i) {
        int g = base + i;
        if (g < V) {
            int h = hist[g];
            offsets[g] = run; cursor[g] = run; run += h;
            if (g == V - 1) offsets[V] = run;       // == N
        }
    }
}

// ---------------- phase 3: scatter indices ----------------
__global__ void scatter_kernel(const int* __restrict__ idx, int* __restrict__ cursor,
                               int* __restrict__ order, int n) {
    int i = blockIdx.x * blockDim.x + threadIdx.x;
    int stride = gridDim.x * blockDim.x;
    for (; i < n; i += stride) {
        int v = idx[i];
        int p = atomicAdd(&cursor[v], 1);
        order[p] = i;
    }
}

// ---------------- phase 4: gather + reduce ----------------
__global__ void __launch_bounds__(BLOCK) reduce_kernel(const float4* __restrict__ H4,
                                                       const int* __restrict__ order,
                                                       const int* __restrict__ offsets,
                                                       float4* __restrict__ out, int V) {
    const int gid  = blockIdx.x * blockDim.x + threadIdx.x;
    const int wave = gid >> 6;          // one wavefront per bucket
    if (wave >= V) return;
    const int lane = gid & 63;
    const int half = lane >> 5;         // 0: even rows, 1: odd rows
    const int col  = lane & 31;         // float4 column within the row (32 per row)

    const int start = offsets[wave];
    const int end   = offsets[wave + 1];
    float4 acc = make_float4(0.f, 0.f, 0.f, 0.f);

    int r = start;
    for (; r + 8 <= end; r += 8) {      // 8 rows in flight via 4 paired loads
        const int na = order[r + 0 + half];
        const int nb = order[r + 2 + half];
        const int nc = order[r + 4 + half];
        const int nd = order[r + 6 + half];
        const float4 a = H4[(size_t)na * 32 + col];
        const float4 b = H4[(size_t)nb * 32 + col];
        const float4 c = H4[(size_t)nc * 32 + col];
        const float4 d = H4[(size_t)nd * 32 + col];
        acc.x += a.x + b.x + c.x + d.x;
        acc.y += a.y + b.y + c.y + d.y;
        acc.z += a.z + b.z + c.z + d.z;
        acc.w += a.w + b.w + c.w + d.w;
    }
    for (; r + 2 <= end; r += 2) {      // paired remainder
        const int n = order[r + half];
        const float4 a = H4[(size_t)n * 32 + col];
        acc.x += a.x; acc.y += a.y; acc.z += a.z; acc.w += a.w;
    }
    if (r < end && half == 0) {         // odd final row: lanes 0-31 only
        const float4 a = H4[(size_t)order[r] * 32 + col];
        acc.x += a.x; acc.y += a.y; acc.z += a.z; acc.w += a.w;
    }
    // combine the two halves (same col, different row parity)
    acc.x += __shfl_xor(acc.x, 32);
    acc.y += __shfl_xor(acc.y, 32);
    acc.z += __shfl_xor(acc.z, 32);
    acc.w += __shfl_xor(acc.w, 32);
    if (half == 0) out[(size_t)wave * 32 + col] = acc;
}

extern "C" void kernel_launch(void* const* d_in, const int* in_sizes, int n_in,
                              void* d_out, int out_size, void* d_ws, size_t ws_size,
                              hipStream_t stream) {
    const float* H      = (const float*)d_in[0];
    const int*   X_node = (const int*)d_in[1];
    const int N = in_sizes[1];
    const int V = out_size / D;
    float* out = (float*)d_out;

    int* hist    = (int*)d_ws;        // V
    int* offsets = hist + V;          // V+1
    int* cursor  = offsets + V + 1;   // V
    int* order   = cursor + V;        // N

    hipMemsetAsync(hist, 0, (size_t)V * sizeof(int), stream);
    hist_kernel<<<2048, BLOCK, 0, stream>>>(X_node, hist, N);
    scan_kernel<<<1, SCAN_T, 0, stream>>>(hist, offsets, cursor, V);
    scatter_kernel<<<2048, BLOCK, 0, stream>>>(X_node, cursor, order, N);
    reduce_kernel<<<((size_t)V * 64 + BLOCK - 1) / BLOCK, BLOCK, 0, stream>>>(
        (const float4*)H, order, offsets, (float4*)out, V);
}

// Round 4
// 380.367 us; speedup vs baseline: 1.2846x; 1.2846x over previous
//
#include <hip/hip_runtime.h>

// Segment-sum via counting sort + gather reduce (no float atomics).
// H: [N=1.6M, 128] f32, X_node: [N] i32, out: [V=50000, 128] f32.
//
// Phases:
//  1. hist[v]   = count of rows with X_node==v           (int atomics)
//  2. offsets   = exclusive scan(hist), offsets[V] = N   (3 small kernels)
//  3. order[]   = row indices grouped by bucket          (int atomics)
//  4. one wave per bucket, lane owns one float2 column; indices for the NEXT
//     8 rows are prefetched while the current 8 row-loads are in flight, so
//     the wave always has ~4 KB of H data outstanding. Single store, no atomics.

#define D 128
#define BLOCK 256
#define CHUNK 1024        // hist elements per scan block
#define K 4               // CHUNK / BLOCK

// ---------------- phase 1: histogram ----------------
__global__ void hist_kernel(const int* __restrict__ idx, int* __restrict__ hist, int n) {
    int i = blockIdx.x * blockDim.x + threadIdx.x;
    int stride = gridDim.x * blockDim.x;
    for (; i < n; i += stride) atomicAdd(&hist[idx[i]], 1);
}

// ---------------- phase 2: scan (3 small kernels) ----------------
__global__ void chunk_sum_kernel(const int* __restrict__ hist, int* __restrict__ bsum, int V) {
    __shared__ int lds[BLOCK];
    const int b = blockIdx.x, t = threadIdx.x;
    const int base = b * CHUNK + t * K;
    int s = 0;
#pragma unroll
    for (int i = 0; i < K; ++i) { int g = base + i; if (g < V) s += hist[g]; }
    lds[t] = s; __syncthreads();
    for (int off = BLOCK / 2; off > 0; off >>= 1) {
        if (t < off) lds[t] += lds[t + off];
        __syncthreads();
    }
    if (t == 0) bsum[b] = lds[0];
}

__global__ void scan_bsum_kernel(int* bsum, int nb) {
    // single block of 64 threads; nb <= 64
    __shared__ int lds[64];
    const int t = threadIdx.x;
    const int v = (t < nb) ? bsum[t] : 0;
    lds[t] = v; __syncthreads();
    for (int off = 1; off < 64; off <<= 1) {
        int add = (t >= off) ? lds[t - off] : 0;
        __syncthreads();
        lds[t] += add;
        __syncthreads();
    }
    if (t < nb) bsum[t] = lds[t] - v;   // exclusive
}

__global__ void chunk_scan_kernel(const int* __restrict__ hist, const int* __restrict__ bsum,
                                  int* __restrict__ offsets, int* __restrict__ cursor,
                                  int V) {
    __shared__ int lds[BLOCK];
    const int b = blockIdx.x, t = threadIdx.x;
    const int base = b * CHUNK + t * K;
    int v[K]; int s = 0;
#pragma unroll
    for (int i = 0; i < K; ++i) { int g = base + i; v[i] = (g < V) ? hist[g] : 0; s += v[i]; }
    lds[t] = s; __syncthreads();
    for (int off = 1; off < BLOCK; off <<= 1) {
        int add = (t >= off) ? lds[t - off] : 0;
        __syncthreads();
        lds[t] += add;
        __syncthreads();
    }
    int run = bsum[b] + lds[t] - s;   // global exclusive prefix for this thread
#pragma unroll
    for (int i = 0; i < K; ++i) {
        int g = base + i;
        if (g < V) {
            offsets[g] = run;
            cursor[g]  = run;
            run += v[i];
            if (g == V - 1) offsets[V] = run;   // == N
        }
    }
}

// ---------------- phase 3: scatter indices ----------------
__global__ void scatter_kernel(const int* __restrict__ idx, int* __restrict__ cursor,
                               int* __restrict__ order, int n) {
    int i = blockIdx.x * blockDim.x + threadIdx.x;
    int stride = gridDim.x * blockDim.x;
    for (; i < n; i += stride) {
        int v = idx[i];
        int p = atomicAdd(&cursor[v], 1);
        order[p] = i;
    }
}

// ---------------- phase 4: pipelined gather + reduce ----------------
__global__ void __launch_bounds__(BLOCK) reduce_kernel(const float2* __restrict__ H2,
                                                       const int* __restrict__ order,
                                                       const int* __restrict__ offsets,
                                                       float2* __restrict__ out, int V) {
    const int gid  = blockIdx.x * blockDim.x + threadIdx.x;
    const int wave = gid >> 6;      // one wavefront (64 lanes) per bucket
    if (wave >= V) return;
    const int lane = gid & 63;      // lane owns float2 at column 2*lane

    const int start = offsets[wave];
    const int end   = offsets[wave + 1];
    float ax = 0.f, ay = 0.f;
    int r = start;

    if (r + 8 <= end) {
        // prologue: indices for the first 8 rows
        int n0 = order[r + 0], n1 = order[r + 1], n2 = order[r + 2], n3 = order[r + 3];
        int n4 = order[r + 4], n5 = order[r + 5], n6 = order[r + 6], n7 = order[r + 7];
        r += 8;
        for (; r + 8 <= end; r += 8) {
            // issue 8 independent row loads (4 KB in flight for this wave)
            const float2 a0 = H2[(size_t)n0 * 64 + lane];
            const float2 a1 = H2[(size_t)n1 * 64 + lane];
            const float2 a2 = H2[(size_t)n2 * 64 + lane];
            const float2 a3 = H2[(size_t)n3 * 64 + lane];
            const float2 a4 = H2[(size_t)n4 * 64 + lane];
            const float2 a5 = H2[(size_t)n5 * 64 + lane];
            const float2 a6 = H2[(size_t)n6 * 64 + lane];
            const float2 a7 = H2[(size_t)n7 * 64 + lane];
            // prefetch next iteration's indices while the row loads are in flight
            n0 = order[r + 0]; n1 = order[r + 1]; n2 = order[r + 2]; n3 = order[r + 3];
            n4 = order[r + 4]; n5 = order[r + 5]; n6 = order[r + 6]; n7 = order[r + 7];
            ax += a0.x + a1.x + a2.x + a3.x + a4.x + a5.x + a6.x + a7.x;
            ay += a0.y + a1.y + a2.y + a3.y + a4.y + a5.y + a6.y + a7.y;
        }
        // drain the last prefetched group
        const float2 a0 = H2[(size_t)n0 * 64 + lane];
        const float2 a1 = H2[(size_t)n1 * 64 + lane];
        const float2 a2 = H2[(size_t)n2 * 64 + lane];
        const float2 a3 = H2[(size_t)n3 * 64 + lane];
        const float2 a4 = H2[(size_t)n4 * 64 + lane];
        const float2 a5 = H2[(size_t)n5 * 64 + lane];
        const float2 a6 = H2[(size_t)n6 * 64 + lane];
        const float2 a7 = H2[(size_t)n7 * 64 + lane];
        ax += a0.x + a1.x + a2.x + a3.x + a4.x + a5.x + a6.x + a7.x;
        ay += a0.y + a1.y + a2.y + a3.y + a4.y + a5.y + a6.y + a7.y;
    }
    // remainder (< 8 rows)
    for (; r < end; ++r) {
        const float2 a = H2[(size_t)order[r] * 64 + lane];
        ax += a.x; ay += a.y;
    }
    out[(size_t)wave * 64 + lane] = make_float2(ax, ay);
}

extern "C" void kernel_launch(void* const* d_in, const int* in_sizes, int n_in,
                              void* d_out, int out_size, void* d_ws, size_t ws_size,
                              hipStream_t stream) {
    const float* H      = (const float*)d_in[0];
    const int*   X_node = (const int*)d_in[1];
    const int N = in_sizes[1];
    const int V = out_size / D;
    float* out = (float*)d_out;

    const int NB = (V + CHUNK - 1) / CHUNK;   // 49 for V=50000

    int* hist    = (int*)d_ws;        // V
    int* offsets = hist + V;          // V+1
    int* cursor  = offsets + V + 1;   // V
    int* order   = cursor + V;        // N
    int* bsum    = order + N;         // NB

    hipMemsetAsync(hist, 0, (size_t)V * sizeof(int), stream);
    hist_kernel<<<2048, BLOCK, 0, stream>>>(X_node, hist, N);
    chunk_sum_kernel<<<NB, BLOCK, 0, stream>>>(hist, bsum, V);
    scan_bsum_kernel<<<1, 64, 0, stream>>>(bsum, NB);
    chunk_scan_kernel<<<NB, BLOCK, 0, stream>>>(hist, bsum, offsets, cursor, V);
    scatter_kernel<<<2048, BLOCK, 0, stream>>>(X_node, cursor, order, N);
    reduce_kernel<<<((size_t)V * 64 + BLOCK - 1) / BLOCK, BLOCK, 0, stream>>>(
        (const float2*)H, order, offsets, (float2*)out, V);
}

// Round 5
// 312.052 us; speedup vs baseline: 1.5658x; 1.2189x over previous
//
#include <hip/hip_runtime.h>

// Segment-sum via direct bucket-table scatter + gather reduce (no float atomics
// in the main path).
// H: [N=1.6M, 128] f32, X_node: [N] i32, out: [V=50000, 128] f32.
//
// Phases:
//  1. scatter: order[v*CAP + atomicAdd(&count[v],1)] = i  (no hist, no scan)
//     rows overflowing CAP go to a tiny overflow list (expected empty).
//  2. reduce:  one wave per bucket, lane owns one float2 column; 8 rows per
//     group with int4-vectorized index loads; final partial group handled with
//     clamped indices + fma masks (no serial dependent tail). Non-temporal
//     loads on H (zero reuse), single non-temporal store per output.
//  3. ovf_fix: atomic-add any overflow rows (no-op for this data).

#define D 128
#define BLOCK 256
#define CAP 128   // per-bucket slot capacity; order table is V*CAP ints

typedef float f2 __attribute__((ext_vector_type(2)));

// ---------------- phase 1: direct scatter ----------------
__global__ void scatter_kernel(const int* __restrict__ idx, int* __restrict__ count,
                               int* __restrict__ order, int* __restrict__ ovf_meta,
                               int* __restrict__ ovf, int n) {
    int i = blockIdx.x * blockDim.x + threadIdx.x;
    int stride = gridDim.x * blockDim.x;
    for (; i < n; i += stride) {
        const int v = idx[i];
        const int p = atomicAdd(&count[v], 1);
        if (p < CAP) {
            order[((unsigned)v << 7) | p] = i;
        } else {
            const int q = atomicAdd(ovf_meta, 1);
            ovf[q] = i;
        }
    }
}

// ---------------- phase 2: gather + reduce ----------------
__global__ void __launch_bounds__(BLOCK) reduce_kernel(const f2* __restrict__ H2,
                                                       const int* __restrict__ count,
                                                       const int* __restrict__ order,
                                                       f2* __restrict__ out, int V) {
    const int gid  = blockIdx.x * blockDim.x + threadIdx.x;
    const int wave = gid >> 6;          // one wavefront per bucket
    if (wave >= V) return;
    const int lane = gid & 63;          // lane owns float2 column `lane`

    int cnt = count[wave];
    if (cnt > CAP) cnt = CAP;           // overflow rows handled by ovf_fix
    const int*  base  = order + ((size_t)wave << 7);
    const int4* base4 = (const int4*)base;

    f2 acc = {0.f, 0.f};
    int g = 0;
    // full groups of 8 rows: 2 int4 index loads + 8 independent 512B row loads
    for (; g + 8 <= cnt; g += 8) {
        const int4 i0 = base4[(g >> 2) + 0];
        const int4 i1 = base4[(g >> 2) + 1];
        const f2 a0 = __builtin_nontemporal_load(H2 + (((unsigned)i0.x << 6) | lane));
        const f2 a1 = __builtin_nontemporal_load(H2 + (((unsigned)i0.y << 6) | lane));
        const f2 a2 = __builtin_nontemporal_load(H2 + (((unsigned)i0.z << 6) | lane));
        const f2 a3 = __builtin_nontemporal_load(H2 + (((unsigned)i0.w << 6) | lane));
        const f2 a4 = __builtin_nontemporal_load(H2 + (((unsigned)i1.x << 6) | lane));
        const f2 a5 = __builtin_nontemporal_load(H2 + (((unsigned)i1.y << 6) | lane));
        const f2 a6 = __builtin_nontemporal_load(H2 + (((unsigned)i1.z << 6) | lane));
        const f2 a7 = __builtin_nontemporal_load(H2 + (((unsigned)i1.w << 6) | lane));
        acc += ((a0 + a1) + (a2 + a3)) + ((a4 + a5) + (a6 + a7));
    }
    // partial group: clamped indices, masked fma — all loads independent,
    // padded lanes re-hit row cnt-1 in L2 (no serial dependent tail).
    if (g < cnt) {
#pragma unroll
        for (int k = 0; k < 7; ++k) {
            const int j  = g + k;
            const int jj = (j < cnt) ? j : (cnt - 1);
            const int n  = base[jj];
            const f2 a = __builtin_nontemporal_load(H2 + (((unsigned)n << 6) | lane));
            const float m = (j < cnt) ? 1.f : 0.f;
            acc.x = fmaf(m, a.x, acc.x);
            acc.y = fmaf(m, a.y, acc.y);
        }
    }
    __builtin_nontemporal_store(acc, out + (((unsigned)wave << 6) | lane));
}

// ---------------- phase 3: overflow fix-up (expected no-op) ----------------
__global__ void ovf_fix_kernel(const f2* __restrict__ H2, const int* __restrict__ idx,
                               const int* __restrict__ ovf_meta, const int* __restrict__ ovf,
                               float* __restrict__ out) {
    const int novf = *ovf_meta;
    if (novf <= 0) return;
    const int gid  = blockIdx.x * blockDim.x + threadIdx.x;
    const int wave = gid >> 6;
    const int lane = gid & 63;
    const int nwaves = (gridDim.x * blockDim.x) >> 6;
    for (int o = wave; o < novf; o += nwaves) {
        const int row = ovf[o];
        const int v   = idx[row];
        const f2 a = H2[(((unsigned)row) << 6) | lane];
        atomicAdd(&out[((unsigned)v << 7) | ((unsigned)lane << 1)],       a.x);
        atomicAdd(&out[(((unsigned)v << 7) | ((unsigned)lane << 1)) + 1], a.y);
    }
}

extern "C" void kernel_launch(void* const* d_in, const int* in_sizes, int n_in,
                              void* d_out, int out_size, void* d_ws, size_t ws_size,
                              hipStream_t stream) {
    const float* H      = (const float*)d_in[0];
    const int*   X_node = (const int*)d_in[1];
    const int N = in_sizes[1];
    const int V = out_size / D;
    float* out = (float*)d_out;

    // ws layout: count[V] | ovf_meta[1] | ovf[N] | order[V*CAP]
    int* count    = (int*)d_ws;
    int* ovf_meta = count + V;
    int* ovf      = ovf_meta + 1;
    int* order    = ovf + N;

    hipMemsetAsync(count, 0, ((size_t)V + 1) * sizeof(int), stream);  // count + ovf_meta

    scatter_kernel<<<2048, BLOCK, 0, stream>>>(X_node, count, order, ovf_meta, ovf, N);

    reduce_kernel<<<((size_t)V * 64 + BLOCK - 1) / BLOCK, BLOCK, 0, stream>>>(
        (const f2*)H, count, order, (f2*)out, V);

    ovf_fix_kernel<<<16, BLOCK, 0, stream>>>((const f2*)H, X_node, ovf_meta, ovf, out);
}